// Round 3
// baseline (204.852 us; speedup 1.0000x reference)
//
#include <hip/hip_runtime.h>
#include <math.h>

#define KQ   32768
#define CC   100
#define BB   1024
#define DD   128
#define NTOT (BB + KQ)        // 33792
#define CB_CENT 1056          // first center cb
#define NCB  1060             // 32-row blocks in X2 (1056 feats + 4 center/pad)
#define NCG2 132              // branch-2 col groups (8 cb each)
#define NCG  141              // + 9 branch-1 col groups (4 cb each)

#define INV_T  14.285714285714286f
#define ALPHA  0.05f
#define EPSV   1e-12f

typedef __attribute__((ext_vector_type(8)))  short          short8;
typedef __attribute__((ext_vector_type(8)))  unsigned short ushort8;
typedef __attribute__((ext_vector_type(16))) float          float16;

__device__ __forceinline__ unsigned short f2bf_rne(float f) {
    unsigned int u = __float_as_uint(f);
    return (unsigned short)((u + 0x7FFFu + ((u >> 16) & 1u)) >> 16);
}

// X2 layout per 32-row block cb (16384 B): [hi|lo][ks 0..7][lane 0..63][16 B]
// element (row r, k): cb=r>>5, ks=k>>4, lane=(r&31)+32*((k>>3)&1), j=k&7
// == 32x32x16 MFMA A/B operand layout (verified R2, absmax 0).

// ---------------- prep: convert + tile (LDS-staged, coalesced), histogram, acc zero ----------------
__global__ __launch_bounds__(256) void prep_k(const float* __restrict__ feats,
                                              const float* __restrict__ centers,
                                              const int* __restrict__ labels,
                                              unsigned short* __restrict__ X2,
                                              int* __restrict__ cntAll,
                                              int* __restrict__ cntBatch,
                                              float* __restrict__ accZ) {
    const int b = blockIdx.x, t = threadIdx.x;
    if (b == NCB) {  // histogram block (runs concurrently with conversion blocks)
        __shared__ int hA[CC], hB[CC];
        if (t < CC) { hA[t] = 0; hB[t] = 0; }
        __syncthreads();
        for (int idx = t; idx < NTOT; idx += 256) {
            int l = labels[idx];
            atomicAdd(&hA[l], 1);
            if (idx < BB) atomicAdd(&hB[l], 1);
        }
        __syncthreads();
        if (t < CC) { cntAll[t] = hA[t]; cntBatch[t] = hB[t]; }
        return;
    }
    if (b < 16) accZ[b * 256 + t] = 0.f;  // zero 4x1024 row accumulators

    __shared__ unsigned short sm[8192];   // 16 KB staging, layout == output block
    const int row = t >> 3, seg = t & 7;
    const int r = b * 32 + row;
    float v[16];
    if (r < NTOT) {
        const float4* p = (const float4*)&feats[(size_t)r * DD + seg * 16];
#pragma unroll
        for (int j = 0; j < 4; ++j) { float4 q = p[j]; v[4*j]=q.x; v[4*j+1]=q.y; v[4*j+2]=q.z; v[4*j+3]=q.w; }
    } else if (r < NTOT + CC) {
        const float4* p = (const float4*)&centers[(size_t)(r - NTOT) * DD + seg * 16];
#pragma unroll
        for (int j = 0; j < 4; ++j) { float4 q = p[j]; v[4*j]=q.x; v[4*j+1]=q.y; v[4*j+2]=q.z; v[4*j+3]=q.w; }
    } else {
#pragma unroll
        for (int j = 0; j < 16; ++j) v[j] = 0.f;
    }
    ushort8 H0, H1, L0, L1;
#pragma unroll
    for (int m = 0; m < 8; ++m) {
        unsigned short hb = f2bf_rne(v[m]);
        float hf = __uint_as_float(((unsigned int)hb) << 16);
        H0[m] = hb; L0[m] = f2bf_rne(v[m] - hf);
        unsigned short hb2 = f2bf_rne(v[m + 8]);
        float hf2 = __uint_as_float(((unsigned int)hb2) << 16);
        H1[m] = hb2; L1[m] = f2bf_rne(v[m + 8] - hf2);
    }
    // halfword index: h*4096 + ks*512 + lane*8
    *(ushort8*)&sm[seg * 512 + row * 8]              = H0;
    *(ushort8*)&sm[seg * 512 + (row + 32) * 8]       = H1;
    *(ushort8*)&sm[4096 + seg * 512 + row * 8]       = L0;
    *(ushort8*)&sm[4096 + seg * 512 + (row + 32) * 8] = L1;
    __syncthreads();
    const ushort8* src = (const ushort8*)sm;
    ushort8* dst = (ushort8*)((char*)X2 + (size_t)b * 16384);
#pragma unroll
    for (int j = 0; j < 4; ++j) dst[j * 256 + t] = src[j * 256 + t];  // 1 KB/wave contiguous
}

// ---------------- fused MFMA GEMM (branch 2 + branch 1), XCD-swizzled ----------------
// grid 1152 = 8 xcd * 18 ci * 8 rt; cg = xcd + 8*ci; cg<132: branch2 (8 cb), 132..140: branch1 (4 cb)
__global__ __launch_bounds__(256, 3) void gemm_k(
    const unsigned short* __restrict__ X2, const int* __restrict__ labels,
    const int* __restrict__ cntAll, const int* __restrict__ cntBatch,
    float* __restrict__ acc4) {
    const int b = blockIdx.x;
    const int xcd = b & 7, l = b >> 3;
    const int rt = l & 7, ci = l >> 3;
    const int cg = xcd + 8 * ci;
    if (cg >= NCG) return;
    const bool isB2 = (cg < NCG2);

    const int tid = threadIdx.x;
    const int lane = tid & 63, w = tid >> 6;
    const int half = lane >> 5, ln = lane & 31;
    const int rb = rt * 4 + w;
    const int growbase = rt * 128 + w * 32;
    const char* Xb = (const char*)X2;

    short8 Ah[8], Al[8];
    {
        size_t abase = (size_t)rb * 16384 + (size_t)lane * 16;
#pragma unroll
        for (int ks = 0; ks < 8; ++ks) {
            Ah[ks] = *(const short8*)(Xb + abase + (size_t)ks * 1024);
            Al[ks] = *(const short8*)(Xb + abase + 8192 + (size_t)ks * 1024);
        }
    }
    int rlab[16];
#pragma unroll
    for (int reg = 0; reg < 16; ++reg) {
        int ro = (reg & 3) + 8 * (reg >> 2) + 4 * half;
        rlab[reg] = labels[growbase + ro];
    }
    float sS[16], sN[16];
#pragma unroll
    for (int reg = 0; reg < 16; ++reg) { sS[reg] = 0.f; sN[reg] = 0.f; }

    const int ncb = isB2 ? 8 : 4;
    const int t1 = cg - NCG2;
    for (int i = 0; i < ncb; ++i) {
        const int cb = isB2 ? (cg * 8 + i) : ((t1 < 8) ? (t1 * 4 + i) : (CB_CENT + i));
        const int ccol = cb * 32 + ln;
        int lc; float rn, rm;
        if (isB2) {
            lc = labels[ccol];
            float c = (float)cntAll[lc];
            rn = __builtin_amdgcn_rcpf(c);
            rm = __builtin_amdgcn_rcpf(c - ALPHA);
        } else {
            if (cb < 32) lc = labels[ccol];
            else { int c = ccol - NTOT; lc = (c < CC) ? c : -1; }
            int cbv = (lc >= 0) ? cntBatch[lc] : 1;
            float c1 = (float)(cbv + 1);
            rn = (lc >= 0) ? __builtin_amdgcn_rcpf(c1) : 0.f;
            rm = (lc >= 0) ? __builtin_amdgcn_rcpf(c1 - 1.0f) : 0.f;
        }
        const bool mayDiag = (cb == rb);  // col block overlaps this wave's rows

        const size_t bbase = (size_t)cb * 16384 + (size_t)lane * 16;
        float16 acc;
#pragma unroll
        for (int reg = 0; reg < 16; ++reg) acc[reg] = 0.f;
#pragma unroll
        for (int ks = 0; ks < 8; ++ks) {
            short8 Bh = *(const short8*)(Xb + bbase + (size_t)ks * 1024);
            short8 Bl = *(const short8*)(Xb + bbase + 8192 + (size_t)ks * 1024);
            acc = __builtin_amdgcn_mfma_f32_32x32x16_bf16(Ah[ks], Bh, acc, 0, 0, 0);
            acc = __builtin_amdgcn_mfma_f32_32x32x16_bf16(Ah[ks], Bl, acc, 0, 0, 0);
            acc = __builtin_amdgcn_mfma_f32_32x32x16_bf16(Al[ks], Bh, acc, 0, 0, 0);
        }
#pragma unroll
        for (int reg = 0; reg < 16; ++reg) {
            int ro = (reg & 3) + 8 * (reg >> 2) + 4 * half;
            int grow = growbase + ro;
            float e = __expf(fmaf(acc[reg], INV_T, -INV_T));  // exp(raw - SHIFT)
            bool m = (lc == rlab[reg]);
            bool diag = mayDiag && (ccol == grow);
            float wgt = diag ? 0.f : (m ? rm : rn);
            sS[reg] = fmaf(e, wgt, sS[reg]);
            float raw = acc[reg] * INV_T;
            sN[reg] += (m && !diag) ? raw : 0.f;
        }
    }
    // cross-lane (32 cols) reduce, then per-row atomic accumulate
    float* aS = isB2 ? (acc4)          : (acc4 + 2048);
    float* aN = isB2 ? (acc4 + 1024)   : (acc4 + 3072);
#pragma unroll
    for (int reg = 0; reg < 16; ++reg) {
        float a = sS[reg], c = sN[reg];
#pragma unroll
        for (int off = 1; off < 32; off <<= 1) {
            a += __shfl_xor(a, off, 64);
            c += __shfl_xor(c, off, 64);
        }
        if (ln == 0) {
            int ro = (reg & 3) + 8 * (reg >> 2) + 4 * half;
            int grow = growbase + ro;
            atomicAdd(&aS[grow], a);
            atomicAdd(&aN[grow], c);
        }
    }
}

// ---------------- finalize: per-row loss + mean, one block ----------------
__global__ __launch_bounds__(1024) void finalize_k(
    const float* __restrict__ sup, const int* __restrict__ labels,
    const int* __restrict__ cntAll, const int* __restrict__ cntBatch,
    const float* __restrict__ acc4, float* __restrict__ out) {
    const int t = threadIdx.x;
    __shared__ float rA[CC], rAm[CC];
    __shared__ float buf[16];
    if (t < CC) {
        float c = (float)cntAll[t];
        rA[t]  = 1.0f / c;
        rAm[t] = 1.0f / (c - 1.0f);
    }
    __syncthreads();
    const int i = t, li = labels[i];
    float S2 = acc4[i], N2 = acc4[1024 + i], S1 = acc4[2048 + i], N1v = acc4[3072 + i];
    const float* srow = &sup[(size_t)i * CC];
    for (int c = 0; c < CC; ++c) {
        float e = __expf(srow[c] - INV_T);
        S2 += e * ((c == li) ? rAm[c] : rA[c]);
    }
    float num2 = srow[li] + ALPHA * N2;
    float cA = (float)cntAll[li];
    float msum2 = 1.0f + ALPHA * (cA - 1.0f);
    float loss2 = -(num2 / msum2 - INV_T - logf(S2 + EPSV));
    float msum1 = (float)cntBatch[li];
    float loss1 = -(N1v / msum1 - INV_T - logf(S1 + EPSV));
    float s = loss1 + loss2;
#pragma unroll
    for (int off = 32; off > 0; off >>= 1) s += __shfl_down(s, off, 64);
    if ((t & 63) == 0) buf[t >> 6] = s;
    __syncthreads();
    if (t < 64) {
        float x = (t < 16) ? buf[t] : 0.f;
#pragma unroll
        for (int off = 8; off > 0; off >>= 1) x += __shfl_down(x, off, 64);
        if (t == 0) out[0] = x / (float)BB;
    }
}

extern "C" void kernel_launch(void* const* d_in, const int* in_sizes, int n_in,
                              void* d_out, int out_size, void* d_ws, size_t ws_size,
                              hipStream_t stream) {
    const float* feats   = (const float*)d_in[0];
    const float* sup     = (const float*)d_in[1];
    const float* centers = (const float*)d_in[2];
    const int*   labels  = (const int*)d_in[3];
    float* out = (float*)d_out;
    char*  wsb = (char*)d_ws;

    const size_t X2_BYTES = (size_t)NCB * 16384;        // 17,367,040
    unsigned short* X2 = (unsigned short*)wsb;
    int* cntAll   = (int*)(wsb + X2_BYTES);             // 128 ints
    int* cntBatch = cntAll + 128;                       // 128 ints
    float* acc4   = (float*)(wsb + X2_BYTES + 1024);    // 4 x 1024 floats (S2,N2,S1,N1)

    prep_k<<<NCB + 1, 256, 0, stream>>>(feats, centers, labels, X2, cntAll, cntBatch, acc4);
    gemm_k<<<8 * 18 * 8, 256, 0, stream>>>(X2, labels, cntAll, cntBatch, acc4);
    finalize_k<<<1, 1024, 0, stream>>>(sup, labels, cntAll, cntBatch, acc4, out);
}